// Round 7
// baseline (274.577 us; speedup 1.0000x reference)
//
#include <hip/hip_runtime.h>
#include <hip/hip_bf16.h>

#define NB 8
#define LQ 512
#define LK 2048
#define EE 512
#define NH 8
#define HD 64
#define NTOPK 20

typedef float f4v __attribute__((ext_vector_type(4)));
typedef unsigned u4v __attribute__((ext_vector_type(4)));
typedef short s8v __attribute__((ext_vector_type(8)));
typedef __bf16 bfrag __attribute__((ext_vector_type(8)));

__device__ inline short f2bf(float f) {
    union { float f; unsigned u; } x; x.f = f;
    unsigned r = (x.u + 0x7FFFu + ((x.u >> 16) & 1u)) >> 16;
    return (short)r;
}
__device__ inline float bf2f(short s) {
    union { unsigned u; float f; } x;
    x.u = ((unsigned)(unsigned short)s) << 16;
    return x.f;
}
__device__ inline float exp2_fast(float x) {   // bare v_exp_f32 (2^x)
    float r;
    asm("v_exp_f32 %0, %1" : "=v"(r) : "v"(x));
    return r;
}

// async global->LDS, 16 B per lane (dest = wave-uniform base + lane*16)
__device__ inline void gld_lds16(const void* g, void* l) {
    __builtin_amdgcn_global_load_lds(
        (const __attribute__((address_space(1))) unsigned*)g,
        (__attribute__((address_space(3))) unsigned*)l, 16, 0, 0);
}

// all-lane 64-wide max butterfly: xor1/2 (quad_perm), xor4/8 (mirrors, VALU),
// xor16 (ds_swizzle), xor32 (ds_bpermute). Result in every lane.
__device__ inline unsigned wave_allmax_u32(unsigned x, int bpaddr) {
    unsigned t;
    t = (unsigned)__builtin_amdgcn_update_dpp(0, (int)x, 0xB1,  0xf, 0xf, true); x = x > t ? x : t;
    t = (unsigned)__builtin_amdgcn_update_dpp(0, (int)x, 0x4E,  0xf, 0xf, true); x = x > t ? x : t;
    t = (unsigned)__builtin_amdgcn_update_dpp(0, (int)x, 0x141, 0xf, 0xf, true); x = x > t ? x : t;
    t = (unsigned)__builtin_amdgcn_update_dpp(0, (int)x, 0x140, 0xf, 0xf, true); x = x > t ? x : t;
    t = (unsigned)__builtin_amdgcn_ds_swizzle((int)x, 0x401F);                   x = x > t ? x : t;
    t = (unsigned)__builtin_amdgcn_ds_bpermute(bpaddr, (int)x);                  x = x > t ? x : t;
    return x;
}
__device__ inline float wave_allsum_f32(float x, int bpaddr) {
    union fi { float f; int i; } a, t;
    a.f = x;
    t.i = __builtin_amdgcn_update_dpp(0, a.i, 0xB1,  0xf, 0xf, true); a.f += t.f;
    t.i = __builtin_amdgcn_update_dpp(0, a.i, 0x4E,  0xf, 0xf, true); a.f += t.f;
    t.i = __builtin_amdgcn_update_dpp(0, a.i, 0x141, 0xf, 0xf, true); a.f += t.f;
    t.i = __builtin_amdgcn_update_dpp(0, a.i, 0x140, 0xf, 0xf, true); a.f += t.f;
    t.i = __builtin_amdgcn_ds_swizzle(a.i, 0x401F);                   a.f += t.f;
    t.i = __builtin_amdgcn_ds_bpermute(bpaddr, a.i);                  a.f += t.f;
    return a.f;
}

// one-shot f32 -> bf16 conversion of q,k,v,Wq,Wk,Wv,Wo
__global__ __launch_bounds__(256) void cvt_all(
    const float* __restrict__ q, const float* __restrict__ k, const float* __restrict__ v,
    const float* __restrict__ wq, const float* __restrict__ wk, const float* __restrict__ wv,
    const float* __restrict__ wo,
    short* __restrict__ qb, short* __restrict__ kb, short* __restrict__ vb,
    short* __restrict__ wqb, short* __restrict__ wkb, short* __restrict__ wvb,
    short* __restrict__ wob)
{
    const float* src; short* dst; int n;
    switch (blockIdx.y) {
        case 0: src = q;  dst = qb;  n = NB * LQ * EE; break;
        case 1: src = k;  dst = kb;  n = NB * LK * EE; break;
        case 2: src = v;  dst = vb;  n = NB * LK * EE; break;
        case 3: src = wq; dst = wqb; n = EE * EE; break;
        case 4: src = wk; dst = wkb; n = EE * EE; break;
        case 5: src = wv; dst = wvb; n = EE * EE; break;
        default: src = wo; dst = wob; n = EE * EE; break;
    }
    const int nv = n >> 3;
    for (int i = blockIdx.x * 256 + threadIdx.x; i < nv; i += gridDim.x * 256) {
        f4v a = *(const f4v*)&src[(size_t)i * 8];
        f4v b = *(const f4v*)&src[(size_t)i * 8 + 4];
        s8v o;
        o[0] = f2bf(a[0]); o[1] = f2bf(a[1]); o[2] = f2bf(a[2]); o[3] = f2bf(a[3]);
        o[4] = f2bf(b[0]); o[5] = f2bf(b[1]); o[6] = f2bf(b[2]); o[7] = f2bf(b[3]);
        *(s8v*)&dst[(size_t)i * 8] = o;
    }
}

// swizzled-LDS fragment read: element (row, bytecol) of a [128][64]-short tile
// stored with byte ^= ((row&7)<<4)
#define LDSW(arr, row, bytecol) \
    (*(const bfrag*)((const char*)(arr) + (row) * 128 + ((bytecol) ^ (((row) & 7) << 4))))

// C[M][512] = A[M][512] @ W[512][512]^T, bf16 in. MODE 0: bf16 out; MODE 2: f32+bias+resid
template<int MODE>
__global__ __launch_bounds__(256) void gemm_bf16(
    const short* __restrict__ A, const short* __restrict__ W,
    void* __restrict__ C, const float* __restrict__ bias,
    const float* __restrict__ resid)
{
    __shared__ short As[128 * 64];   // 16 KB, XOR-swizzled rows
    __shared__ short Bs[128 * 64];
    const int tid  = threadIdx.x;
    const int lane = tid & 63;
    const int wid  = tid >> 6;
    const int wr   = (tid >> 7) & 1;
    const int wc   = (tid >> 6) & 1;
    const size_t bm = (size_t)blockIdx.y * 128;
    const int    bn = blockIdx.x * 128;

    f4v acc[4][4] = {};
    const int lr = lane & 15;
    const int kg = (lane >> 4) * 8;
    const int srow = wid * 8 + (lane >> 3);   // staged row within 32-slab
    const int scol = (lane & 7) * 16;         // byte col of the lane's LDS slot

    for (int ks = 0; ks < EE; ks += 64) {
        #pragma unroll
        for (int i = 0; i < 4; i++) {
            const int r  = i * 32 + srow;
            const int gc = scol ^ ((r & 7) << 4);   // inverse-swizzled source col
            gld_lds16((const char*)&A[(bm + r) * EE + ks] + gc,
                      (char*)As + (i * 32 + wid * 8) * 128);
            gld_lds16((const char*)&W[((size_t)bn + r) * EE + ks] + gc,
                      (char*)Bs + (i * 32 + wid * 8) * 128);
        }
        __syncthreads();
        #pragma unroll
        for (int kk = 0; kk < 64; kk += 32) {
            bfrag af[4], bf[4];
            #pragma unroll
            for (int mi = 0; mi < 4; mi++) {
                const int ar = wr * 64 + mi * 16 + lr;
                af[mi] = LDSW(As, ar, (kk + kg) * 2);
            }
            #pragma unroll
            for (int ni = 0; ni < 4; ni++) {
                const int br = wc * 64 + ni * 16 + lr;
                bf[ni] = LDSW(Bs, br, (kk + kg) * 2);
            }
            #pragma unroll
            for (int mi = 0; mi < 4; mi++)
                #pragma unroll
                for (int ni = 0; ni < 4; ni++)
                    acc[mi][ni] = __builtin_amdgcn_mfma_f32_16x16x32_bf16(
                        af[mi], bf[ni], acc[mi][ni], 0, 0, 0);
        }
        __syncthreads();
    }

    const int rj = (lane >> 4) * 4;
    #pragma unroll
    for (int mi = 0; mi < 4; mi++) {
        #pragma unroll
        for (int ni = 0; ni < 4; ni++) {
            const int    col  = bn + wc * 64 + ni * 16 + lr;
            const size_t row0 = bm + wr * 64 + mi * 16 + rj;
            #pragma unroll
            for (int j = 0; j < 4; j++) {
                const float  v   = acc[mi][ni][j];
                const size_t idx = (row0 + j) * EE + col;
                if (MODE == 0) ((short*)C)[idx] = f2bf(v);
                else           ((float*)C)[idx] = v + bias[col] + resid[idx];
            }
        }
    }
}

// S'[z][m][n] = (log2e/8) * sum_k Qp[b][m][h*64+k] * Kp[b][n][h*64+k], bf16, z=b*8+h
__global__ __launch_bounds__(256) void score_gemm(
    const short* __restrict__ Qp, const short* __restrict__ Kp,
    short* __restrict__ Sg)
{
    __shared__ short As[128 * 64];
    __shared__ short Bs[128 * 64];
    const int tid  = threadIdx.x;
    const int lane = tid & 63;
    const int wid  = tid >> 6;
    const int wr   = (tid >> 7) & 1;
    const int wc   = (tid >> 6) & 1;
    const int z  = blockIdx.z;
    const int h  = z & 7;
    const int b  = z >> 3;
    const int bm = blockIdx.y * 128;
    const int bn = blockIdx.x * 128;

    const short* Ab = Qp + (size_t)b * LQ * EE + h * HD;
    const short* Bb = Kp + (size_t)b * LK * EE + h * HD;

    const int srow = wid * 8 + (lane >> 3);
    const int scol = (lane & 7) * 16;
    #pragma unroll
    for (int i = 0; i < 4; i++) {
        const int r  = i * 32 + srow;
        const int gc = scol ^ ((r & 7) << 4);
        gld_lds16((const char*)&Ab[(size_t)(bm + r) * EE] + gc,
                  (char*)As + (i * 32 + wid * 8) * 128);
        gld_lds16((const char*)&Bb[(size_t)(bn + r) * EE] + gc,
                  (char*)Bs + (i * 32 + wid * 8) * 128);
    }
    __syncthreads();

    f4v acc[4][4] = {};
    const int lr = lane & 15;
    const int kg = (lane >> 4) * 8;
    #pragma unroll
    for (int kk = 0; kk < HD; kk += 32) {
        bfrag af[4], bf[4];
        #pragma unroll
        for (int mi = 0; mi < 4; mi++) {
            const int ar = wr * 64 + mi * 16 + lr;
            af[mi] = LDSW(As, ar, (kk + kg) * 2);
        }
        #pragma unroll
        for (int ni = 0; ni < 4; ni++) {
            const int br = wc * 64 + ni * 16 + lr;
            bf[ni] = LDSW(Bs, br, (kk + kg) * 2);
        }
        #pragma unroll
        for (int mi = 0; mi < 4; mi++)
            #pragma unroll
            for (int ni = 0; ni < 4; ni++)
                acc[mi][ni] = __builtin_amdgcn_mfma_f32_16x16x32_bf16(
                    af[mi], bf[ni], acc[mi][ni], 0, 0, 0);
    }

    short* Sh = Sg + (size_t)z * LQ * LK;
    const int rj = (lane >> 4) * 4;
    #pragma unroll
    for (int mi = 0; mi < 4; mi++) {
        #pragma unroll
        for (int ni = 0; ni < 4; ni++) {
            const int col = bn + wc * 64 + ni * 16 + lr;
            const int r0  = bm + wr * 64 + mi * 16 + rj;
            #pragma unroll
            for (int j = 0; j < 4; j++)
                Sh[(size_t)(r0 + j) * LK + col] = f2bf(acc[mi][ni][j] * 0.18033688f);
        }
    }
}

// one wave per query row; packed-key top-20 (per-lane top-3 + all-lane butterfly
// max), no max-subtraction (exp2-domain scores ~N(0,1): f32-safe), deferred
// parallel unpack, vectorized PV. key = mono(bf16 s') << 11 | (2047 - idx).
__global__ __launch_bounds__(256) void topk_pv(
    const unsigned short* __restrict__ Sg, const short* __restrict__ Vp,
    short* __restrict__ attn)
{
    __shared__ float    wp[4][24];    // 24: rows stay 16B-aligned for f4v reads
    __shared__ unsigned widx[4][24];
    const int lane = threadIdx.x & 63;
    const int wid  = threadIdx.x >> 6;
    const int r  = blockIdx.x * 4 + wid;     // 0..32767
    const int h  = (r >> 9) & 7;
    const int qi = r & 511;
    const int b  = r >> 12;
    const unsigned short* Srow = Sg + (size_t)r * LK;
    const int bpaddr = (lane ^ 32) << 2;

    // lane holds indices idx = t*512 + lane*8 + e
    s8v raw[4];
    #pragma unroll
    for (int t = 0; t < 4; t++)
        raw[t] = *(const s8v*)&Srow[t * 512 + lane * 8];

    // denominator over all 2048: sum of 2^s' (no max subtraction; 4-way ILP)
    float p0 = 0.f, p1 = 0.f, p2 = 0.f, p3 = 0.f;
    #pragma unroll
    for (int e = 0; e < 8; e++) {
        p0 += exp2_fast(bf2f(raw[0][e]));
        p1 += exp2_fast(bf2f(raw[1][e]));
        p2 += exp2_fast(bf2f(raw[2][e]));
        p3 += exp2_fast(bf2f(raw[3][e]));
    }
    float sum = wave_allsum_f32((p0 + p1) + (p2 + p3), bpaddr);
    const float inv = __builtin_amdgcn_rcpf(sum);

    // fused key-build + per-lane sorted top-3
    const unsigned invl = 2047u - (unsigned)(lane * 8);
    unsigned v1 = 0, v2 = 0, v3 = 0;
    #pragma unroll
    for (int t = 0; t < 4; t++) {
        #pragma unroll
        for (int e = 0; e < 8; e++) {
            const unsigned u   = (unsigned short)raw[t][e];
            const unsigned sgn = (unsigned)((int)(u << 16) >> 31);
            const unsigned kc  = ((u ^ (0x8000u | (sgn & 0x7FFFu))) << 11)
                               | (invl - (unsigned)(t * 512 + e));
            const unsigned m1 = v1 < kc ? v1 : kc;
            v1 = v1 > kc ? v1 : kc;
            const unsigned m2 = v2 < m1 ? v2 : m1;
            v2 = v2 > m1 ? v2 : m1;
            v3 = v3 > m2 ? v3 : m2;
        }
    }

    // selection loop: winner key captured per-lane via cndmask; pop owner;
    // rare top-3 rebuild when a lane's cache empties
    unsigned K = wave_allmax_u32(v1, bpaddr);
    unsigned rm = 0, mykey = 0;
    #pragma unroll 1
    for (int kk = 0; kk < NTOPK; kk++) {
        mykey = (lane == kk) ? K : mykey;
        if (v1 == K) {                       // unique owner (index in key)
            const unsigned idx  = 2047u - (K & 2047u);
            const unsigned slot = ((idx >> 9) << 3) | (idx & 7u);
            rm |= (1u << slot);
            v1 = v2; v2 = v3; v3 = 0;
        }
        if (__any(v1 == 0u)) {               // rare: rebuild owner's top-3
            if (v1 == 0u) {
                unsigned a1 = 0, a2 = 0, a3 = 0;
                #pragma unroll
                for (int t = 0; t < 4; t++) {
                    #pragma unroll
                    for (int e = 0; e < 8; e++) {
                        const int c = t * 8 + e;
                        const unsigned u   = (unsigned short)raw[t][e];
                        const unsigned sgn = (unsigned)((int)(u << 16) >> 31);
                        unsigned kc = ((u ^ (0x8000u | (sgn & 0x7FFFu))) << 11)
                                    | (invl - (unsigned)(t * 512 + e));
                        kc = ((rm >> c) & 1u) ? 0u : kc;
                        const unsigned m1 = a1 < kc ? a1 : kc;
                        a1 = a1 > kc ? a1 : kc;
                        const unsigned m2 = a2 < m1 ? a2 : m1;
                        a2 = a2 > m1 ? a2 : m1;
                        a3 = a3 > m2 ? a3 : m2;
                    }
                }
                v1 = a1; v2 = a2; v3 = a3;
            }
        }
        K = wave_allmax_u32(v1, bpaddr);
    }

    // parallel unpack: lane kk holds winner kk
    if (lane < NTOPK) {
        const unsigned idx = 2047u - (mykey & 2047u);
        const unsigned mo  = mykey >> 11;
        const unsigned sb  = (mo & 0x8000u) ? (mo ^ 0x8000u) : (~mo & 0xFFFFu);
        union { unsigned u; float f; } su; su.u = sb << 16;
        wp[wid][lane]   = exp2_fast(su.f) * inv;
        widx[wid][lane] = idx;
    }
    __syncthreads();

    // PV: vector-load the 20 (p, idx), then 20 independent coalesced gathers
    f4v pw[5]; u4v iw[5];
    #pragma unroll
    for (int j = 0; j < 5; j++) {
        pw[j] = *(const f4v*)&wp[wid][j * 4];
        iw[j] = *(const u4v*)&widx[wid][j * 4];
    }
    float oacc = 0.f;
    const short* Vb = Vp + (size_t)b * LK * EE + h * HD + lane;
    #pragma unroll
    for (int kk = 0; kk < NTOPK; kk++)
        oacc += pw[kk >> 2][kk & 3] * bf2f(Vb[(size_t)iw[kk >> 2][kk & 3] * EE]);

    attn[((size_t)b * LQ + qi) * EE + h * HD + lane] = f2bf(oacc);
}

extern "C" void kernel_launch(void* const* d_in, const int* in_sizes, int n_in,
                              void* d_out, int out_size, void* d_ws, size_t ws_size,
                              hipStream_t stream)
{
    const float* q  = (const float*)d_in[0];
    const float* k  = (const float*)d_in[1];
    const float* v  = (const float*)d_in[2];
    const float* Wq = (const float*)d_in[3];
    const float* Wk = (const float*)d_in[4];
    const float* Wv = (const float*)d_in[5];
    const float* Wo = (const float*)d_in[6];
    const float* bo = (const float*)d_in[7];

    if (ws_size < ((size_t)208 << 20)) return;

    char*  ws  = (char*)d_ws;
    short* qb  = (short*)(ws);                        //  4 MiB bf16 [8,512,512]
    short* kb  = (short*)(ws + ((size_t)4   << 20));  // 16 MiB bf16 [8,2048,512]
    short* vb  = (short*)(ws + ((size_t)20  << 20));  // 16 MiB
    short* wqb = (short*)(ws + ((size_t)36  << 20));  // 0.5 MiB each
    short* wkb = (short*)(ws + ((size_t)36  << 20) + (512 << 10));
    short* wvb = (short*)(ws + ((size_t)37  << 20));
    short* wob = (short*)(ws + ((size_t)37  << 20) + (512 << 10));
    short* Qp  = (short*)(ws + ((size_t)38  << 20));  //  4 MiB bf16 [8,512,512]
    short* Kp  = (short*)(ws + ((size_t)42  << 20));  // 16 MiB bf16 [8,2048,512]
    short* Vp  = (short*)(ws + ((size_t)58  << 20));  // 16 MiB bf16 [8,2048,512]
    short* att = (short*)(ws + ((size_t)74  << 20));  //  4 MiB bf16 [8,512,512]
    short* Sg  = (short*)(ws + ((size_t)80  << 20));  // 128 MiB bf16 [8,8,512,2048]

    dim3 blk(256);
    cvt_all<<<dim3(512, 7), blk, 0, stream>>>(q, k, v, Wq, Wk, Wv, Wo,
                                              qb, kb, vb, wqb, wkb, wvb, wob);

    gemm_bf16<0><<<dim3(4, 32),  blk, 0, stream>>>(qb, wqb, Qp, nullptr, nullptr);
    gemm_bf16<0><<<dim3(4, 128), blk, 0, stream>>>(kb, wkb, Kp, nullptr, nullptr);
    gemm_bf16<0><<<dim3(4, 128), blk, 0, stream>>>(vb, wvb, Vp, nullptr, nullptr);

    score_gemm<<<dim3(LK / 128, LQ / 128, NB * NH), blk, 0, stream>>>(Qp, Kp, Sg);
    topk_pv<<<dim3(NB * NH * LQ / 4), blk, 0, stream>>>((const unsigned short*)Sg, Vp, att);

    gemm_bf16<2><<<dim3(4, 32), blk, 0, stream>>>(att, wob, (float*)d_out, bo, q);
}